// Round 1
// baseline (2963.878 us; speedup 1.0000x reference)
//
#include <hip/hip_runtime.h>
#include <math.h>

#define B_  64
#define S_  64
#define I_  64
#define O_  64
#define N_  1024
#define M_  64
#define H_  256
#define G4  1024   // 4*H
#define P_  268    // 4*M+12
#define EPSF 1e-8f

__device__ __forceinline__ float sigmoidf_(float x){ return 1.0f/(1.0f+expf(-x)); }
__device__ __forceinline__ float softplusf_(float x){ return fmaxf(x,0.0f)+log1pf(expf(-fabsf(x))); }

__device__ __forceinline__ float2 block_sum2(float2 v, float2* redbuf){
  int tid=threadIdx.x, lane=tid&63, wid=tid>>6;
  #pragma unroll
  for(int t=32;t;t>>=1){ v.x+=__shfl_xor(v.x,t,64); v.y+=__shfl_xor(v.y,t,64); }
  if(lane==0) redbuf[wid]=v;
  __syncthreads();
  float2 a=redbuf[0];
  #pragma unroll
  for(int i=1;i<16;i++){ float2 t2=redbuf[i]; a.x+=t2.x; a.y+=t2.y; }
  __syncthreads();
  return a;
}

__device__ __forceinline__ float2 block_max2(float2 v, float2* redbuf){
  int tid=threadIdx.x, lane=tid&63, wid=tid>>6;
  #pragma unroll
  for(int t=32;t;t>>=1){ v.x=fmaxf(v.x,__shfl_xor(v.x,t,64)); v.y=fmaxf(v.y,__shfl_xor(v.y,t,64)); }
  if(lane==0) redbuf[wid]=v;
  __syncthreads();
  float2 a=redbuf[0];
  #pragma unroll
  for(int i=1;i<16;i++){ float2 t2=redbuf[i]; a.x=fmaxf(a.x,t2.x); a.y=fmaxf(a.y,t2.y); }
  __syncthreads();
  return a;
}

extern "C" __global__ __launch_bounds__(1024)
void ntm_persistent(const float* __restrict__ X,    // B,S,I
                    const float* __restrict__ Wx,   // 128 x 1024
                    const float* __restrict__ Wh,   // 256 x 1024
                    const float* __restrict__ bl,   // 1024
                    const float* __restrict__ Whd,  // 256 x 268
                    const float* __restrict__ bh,   // 268
                    const float* __restrict__ Wo,   // 320 x 64
                    const float* __restrict__ bo,   // 64
                    float* __restrict__ out,        // B,S,O
                    float* __restrict__ ws_mem)     // B*N*M scratch
{
  const int b    = blockIdx.x;
  const int tid  = threadIdx.x;
  const int lane = tid & 63;
  const int wid  = tid >> 6;

  __shared__ float h_s[H_], c_s[H_], r_s[M_], xr[I_+M_];
  __shared__ float gates[G4];
  __shared__ float p_s[P_];
  __shared__ float k_r[M_], k_w[M_], e_s[M_], a_s[M_];
  __shared__ float w_r[N_], w_w[N_];
  __shared__ float wg_r[N_], wg_w[N_];
  __shared__ float part[16][M_];
  __shared__ float2 redbuf[16];
  __shared__ float sc_beta_r, sc_g_r, sc_s_r0, sc_s_r1, sc_s_r2, sc_gamma_r;
  __shared__ float sc_beta_w, sc_g_w, sc_s_w0, sc_s_w1, sc_s_w2, sc_gamma_w;
  __shared__ float nk_r, nk_w;

  float* mem = ws_mem + (size_t)b * (N_*M_);

  // ---- per-launch init (ws/d_out are re-poisoned by harness every call) ----
  for(int i=tid;i<N_*M_;i+=1024) mem[i] = 0.01f;
  if(tid<H_){ h_s[tid]=0.f; c_s[tid]=0.f; }
  if(tid<M_) r_s[tid]=0.f;
  w_r[tid] = (tid==0)?1.f:0.f;
  w_w[tid] = (tid==0)?1.f:0.f;
  __syncthreads();

  for(int s=0;s<S_;s++){
    // ---- build [x_t, r] ----
    if(tid<I_)            xr[tid] = X[((size_t)b*S_+s)*I_+tid];
    else if(tid<I_+M_)    xr[tid] = r_s[tid-I_];
    __syncthreads();

    // ---- gates = [x,r]@Wx + h@Wh + b  (thread = output column) ----
    {
      float acc = bl[tid];
      #pragma unroll 4
      for(int i=0;i<I_+M_;i++) acc += xr[i]*Wx[i*G4+tid];
      #pragma unroll 4
      for(int k=0;k<H_;k++)    acc += h_s[k]*Wh[k*G4+tid];
      gates[tid]=acc;
    }
    __syncthreads();

    // ---- LSTM pointwise (i,f,g,o are 256-col chunks) ----
    if(tid<H_){
      float ig=gates[tid], fg=gates[256+tid], gg=gates[512+tid], og=gates[768+tid];
      float cn = sigmoidf_(fg)*c_s[tid] + sigmoidf_(ig)*tanhf(gg);
      c_s[tid]=cn;
      h_s[tid]=sigmoidf_(og)*tanhf(cn);
    }
    __syncthreads();

    // ---- p = h @ W_head + b_head ----
    if(tid<P_){
      float acc = bh[tid];
      #pragma unroll 4
      for(int k=0;k<H_;k++) acc += h_s[k]*Whd[k*P_+tid];
      p_s[tid]=acc;
    }
    __syncthreads();

    // ---- parse heads ----
    if(wid==0){               // read-head key + norm
      float kv = tanhf(p_s[lane]); k_r[lane]=kv;
      float sq = kv*kv;
      #pragma unroll
      for(int t=32;t;t>>=1) sq += __shfl_xor(sq,t,64);
      if(lane==0) nk_r = sqrtf(sq);
    } else if(wid==1){        // write-head key + norm
      float kv = tanhf(p_s[70+lane]); k_w[lane]=kv;
      float sq = kv*kv;
      #pragma unroll
      for(int t=32;t;t>>=1) sq += __shfl_xor(sq,t,64);
      if(lane==0) nk_w = sqrtf(sq);
    } else if(wid==2){        // erase
      e_s[lane] = sigmoidf_(p_s[140+lane]);
    } else if(wid==3){        // add
      a_s[lane] = p_s[204+lane];
    } else if(tid==256){      // read-head scalars
      sc_beta_r = softplusf_(p_s[64]);
      sc_g_r    = sigmoidf_(p_s[65]);
      float m3=fmaxf(p_s[66],fmaxf(p_s[67],p_s[68]));
      float e0=expf(p_s[66]-m3), e1=expf(p_s[67]-m3), e2=expf(p_s[68]-m3);
      float ss=e0+e1+e2;
      sc_s_r0=e0/ss; sc_s_r1=e1/ss; sc_s_r2=e2/ss;
      sc_gamma_r = 1.0f+softplusf_(p_s[69]);
    } else if(tid==320){      // write-head scalars
      sc_beta_w = softplusf_(p_s[134]);
      sc_g_w    = sigmoidf_(p_s[135]);
      float m3=fmaxf(p_s[136],fmaxf(p_s[137],p_s[138]));
      float e0=expf(p_s[136]-m3), e1=expf(p_s[137]-m3), e2=expf(p_s[138]-m3);
      float ss=e0+e1+e2;
      sc_s_w0=e0/ss; sc_s_w1=e1/ss; sc_s_w2=e2/ss;
      sc_gamma_w = 1.0f+softplusf_(p_s[139]);
    }
    __syncthreads();

    // ---- addressing pass 1: dot + row norm (thread n = tid) ----
    float dot_r=0.f, dot_w=0.f, nsq=0.f;
    {
      const float* row = mem + (size_t)tid*M_;
      #pragma unroll 4
      for(int m=0;m<M_;m+=4){
        float4 v = *reinterpret_cast<const float4*>(row+m);
        dot_r += v.x*k_r[m]   + v.y*k_r[m+1] + v.z*k_r[m+2] + v.w*k_r[m+3];
        dot_w += v.x*k_w[m]   + v.y*k_w[m+1] + v.z*k_w[m+2] + v.w*k_w[m+3];
        nsq   += v.x*v.x + v.y*v.y + v.z*v.z + v.w*v.w;
      }
    }
    float nmem = sqrtf(nsq);
    float sim_r = dot_r/(nk_r*nmem+EPSF);
    float sim_w = dot_w/(nk_w*nmem+EPSF);
    float scr = sc_beta_r*sim_r, scw = sc_beta_w*sim_w;
    float2 mx = block_max2(make_float2(scr,scw), redbuf);
    float er = expf(scr-mx.x), ew = expf(scw-mx.y);
    float2 sm = block_sum2(make_float2(er,ew), redbuf);
    float wc_r = er/sm.x, wc_w = ew/sm.y;

    // interpolate
    float wgr = sc_g_r*wc_r + (1.f-sc_g_r)*w_r[tid];
    float wgw = sc_g_w*wc_w + (1.f-sc_g_w)*w_w[tid];
    wg_r[tid]=wgr; wg_w[tid]=wgw;
    __syncthreads();

    // circular shift + sharpen
    int np1=(tid+1)&(N_-1), nm1=(tid+N_-1)&(N_-1);
    float wsr = sc_s_r0*wg_r[np1] + sc_s_r1*wgr + sc_s_r2*wg_r[nm1];
    float wsw = sc_s_w0*wg_w[np1] + sc_s_w1*wgw + sc_s_w2*wg_w[nm1];
    float wpr = powf(wsr, sc_gamma_r);
    float wpw = powf(wsw, sc_gamma_w);
    float2 sp = block_sum2(make_float2(wpr,wpw), redbuf);
    float wnr = wpr/(sp.x+EPSF), wnw = wpw/(sp.y+EPSF);
    w_r[tid]=wnr; w_w[tid]=wnw;
    __syncthreads();

    // ---- pass 2: r = w_r@mem (pre-update) fused with mem update ----
    // wave wid owns slots n in [wid*64, wid*64+64), lane = column m
    float racc = 0.f;
    {
      const float em = e_s[lane], am = a_s[lane];
      #pragma unroll 4
      for(int nn=0;nn<64;nn++){
        int n = (wid<<6)+nn;
        float wrn = w_r[n], wwn = w_w[n];
        float v = mem[(size_t)n*M_+lane];
        racc += wrn*v;
        mem[(size_t)n*M_+lane] = v*(1.f - wwn*em) + wwn*am;
      }
    }
    part[wid][lane]=racc;
    __syncthreads();
    if(tid<M_){
      float acc=0.f;
      #pragma unroll
      for(int g2=0;g2<16;g2++) acc+=part[g2][tid];
      r_s[tid]=acc;
    }
    __syncthreads();

    // ---- out = [h, r] @ W_out + b_out  (16 k-chunks of 20 x 64 cols) ----
    {
      float acc=0.f;
      int k0=wid*20;
      #pragma unroll
      for(int kk=0;kk<20;kk++){
        int k=k0+kk;
        float hv = (k<H_)? h_s[k] : r_s[k-H_];
        acc += hv*Wo[k*O_+lane];
      }
      part[wid][lane]=acc;
    }
    __syncthreads();
    if(tid<O_){
      float acc=bo[tid];
      #pragma unroll
      for(int g2=0;g2<16;g2++) acc+=part[g2][tid];
      out[((size_t)b*S_+s)*O_+tid]=acc;
    }
    __syncthreads();
  }
}

extern "C" void kernel_launch(void* const* d_in, const int* in_sizes, int n_in,
                              void* d_out, int out_size, void* d_ws, size_t ws_size,
                              hipStream_t stream)
{
  const float* X   = (const float*)d_in[0];
  const float* Wx  = (const float*)d_in[1];
  const float* Wh  = (const float*)d_in[2];
  const float* bl  = (const float*)d_in[3];
  const float* Whd = (const float*)d_in[4];
  const float* bh  = (const float*)d_in[5];
  const float* Wo  = (const float*)d_in[6];
  const float* bo  = (const float*)d_in[7];
  float* out = (float*)d_out;
  float* mem = (float*)d_ws;   // needs 64*1024*64*4 = 16 MB

  hipLaunchKernelGGL(ntm_persistent, dim3(B_), dim3(1024), 0, stream,
                     X, Wx, Wh, bl, Whd, bh, Wo, bo, out, mem);
}